// Round 6
// baseline (195.931 us; speedup 1.0000x reference)
//
#include <hip/hip_runtime.h>

#define NUM_NETS     100000
#define PINS_PER_NET 5
#define NUM_PINS     (NUM_NETS * PINS_PER_NET)
#define NB           512
#define BIN_H        1.953125f          /* 1000/512, exact in fp32 */
#define INV_H        0.512f             /* 512/1000 */
#define OUT_SCALE    (1.0f / 195.3125f) /* 1/(BIN_SIZE_X * 100 tracks) */

#define SW           8                  /* stripe width (bins in x) */
#define NSTRIPES     (NB / SW)          /* 64 */
#define CAP          24576              /* items per stripe bucket (worst ~15.2K) */

// ---------------------------------------------------------------------------
// K_A: bbox + emit 16B items {x, y, s*wh, s*wv} into per-stripe buckets.
// Each net -> 4 corner clusters; cluster (kx,kx+1)x(ky,ky+1) goes to stripe
// kx>>3 (and (kx+1)>>3 on straddle). Block-level LDS count -> one global
// atomic per stripe per block -> dense ranked emission.
// ---------------------------------------------------------------------------
__global__ __launch_bounds__(256) void bbox_emit_kernel(
        const float* __restrict__ pin_pos,
        const int*   __restrict__ flat_netpin,
        const float* __restrict__ net_weights,
        int* __restrict__ gcur,
        float4* __restrict__ bucket) {
    __shared__ int lcnt[NSTRIPES];
    __shared__ int lbase[NSTRIPES];
    int tid = threadIdx.x;
    if (tid < NSTRIPES) lcnt[tid] = 0;
    __syncthreads();

    int n = blockIdx.x * 256 + tid;
    bool valid = n < NUM_NETS;
    float xmn = 1e30f, xmx = -1e30f, ymn = 1e30f, ymx = -1e30f;
    float wh = 0.f, wv = 0.f;
    int kx1 = 0, kx2 = 0;
    if (valid) {
#pragma unroll
        for (int p = 0; p < PINS_PER_NET; ++p) {
            int pi  = flat_netpin[n * PINS_PER_NET + p];
            float x = pin_pos[pi];
            float y = pin_pos[NUM_PINS + pi];
            xmn = fminf(xmn, x); xmx = fmaxf(xmx, x);
            ymn = fminf(ymn, y); ymx = fmaxf(ymx, y);
        }
        float w = net_weights[n];
        wh = w / (ymx - ymn);
        wv = w / (xmx - xmn);
        kx1 = min(NB - 1, (int)(xmn * INV_H));
        kx2 = min(NB - 1, (int)(xmx * INV_H));
        /* count: clusters (xmn,*) x2 at kx1, (xmx,*) x2 at kx2 */
#pragma unroll
        for (int cx = 0; cx < 2; ++cx) {
            int kx = cx ? kx2 : kx1;
            int s0 = kx >> 3;
            atomicAdd(&lcnt[s0], 2);
            if (kx + 1 < NB && ((kx + 1) >> 3) != s0)
                atomicAdd(&lcnt[(kx + 1) >> 3], 2);
        }
    }
    __syncthreads();
    if (tid < NSTRIPES) {
        lbase[tid] = atomicAdd(&gcur[tid], lcnt[tid]);
        lcnt[tid] = 0;
    }
    __syncthreads();
    if (valid) {
#pragma unroll
        for (int cx = 0; cx < 2; ++cx) {
            int   kx = cx ? kx2 : kx1;
            float xc = cx ? xmx : xmn;
            int s0 = kx >> 3;
            int s1 = (kx + 1 < NB) ? ((kx + 1) >> 3) : s0;
#pragma unroll
            for (int cy = 0; cy < 2; ++cy) {
                float yc = cy ? ymx : ymn;
                float sg = ((cx ^ cy) ? -1.0f : 1.0f);
                float4 item = make_float4(xc, yc, sg * wh, sg * wv);
                {
                    int rank = atomicAdd(&lcnt[s0], 1);
                    int pos  = lbase[s0] + rank;
                    if (pos < CAP) bucket[(size_t)s0 * CAP + pos] = item;
                }
                if (s1 != s0) {
                    int rank = atomicAdd(&lcnt[s1], 1);
                    int pos  = lbase[s1] + rank;
                    if (pos < CAP) bucket[(size_t)s1 * CAP + pos] = item;
                }
            }
        }
    }
}

// ---------------------------------------------------------------------------
// K_B: one block per stripe (8 x-rows full y-height in LDS).
// accumulate items -> y-scan (serial-4 + Hillis-Steele over 128) ->
// x-partial scan + totals -> dump scanned partials.
// ---------------------------------------------------------------------------
__global__ __launch_bounds__(1024) void stripe_kernel(
        const float4* __restrict__ bucket,
        const int* __restrict__ gcur,
        float* __restrict__ UpH, float* __restrict__ UpV,
        float* __restrict__ Th,  float* __restrict__ Tv) {
    __shared__ float acc[2 * SW * NB];          /* 32 KB: H then V */
    float* accH = acc;
    float* accV = acc + SW * NB;
    int st  = blockIdx.x;
    int tid = threadIdx.x;
    int x0  = st * SW;

    float4* a4 = (float4*)acc;
#pragma unroll
    for (int k = tid; k < 2 * SW * NB / 4; k += 1024)
        a4[k] = make_float4(0.f, 0.f, 0.f, 0.f);
    __syncthreads();

    int cnt = min(gcur[st], CAP);
    for (int q = tid; q < cnt; q += 1024) {
        float4 it = bucket[(size_t)st * CAP + q];
        int kx = min(NB - 1, (int)(it.x * INV_H));
        int ky = min(NB - 1, (int)(it.y * INV_H));
        float dx0 = (kx + 1) * BIN_H - it.x;
        float dx1 = it.x - kx * BIN_H;
        float dy0 = (ky + 1) * BIN_H - it.y;
        float dy1 = it.y - ky * BIN_H;
        bool y1ok = (ky + 1) < NB;
        int c = kx - x0;
#pragma unroll
        for (int cc = 0; cc < 2; ++cc) {
            int col = c + cc;
            if ((unsigned)col < SW) {
                float dx = cc ? dx1 : dx0;
                int b = col * NB + ky;
                atomicAdd(&accH[b], it.z * dx * dy0);
                atomicAdd(&accV[b], it.w * dx * dy0);
                if (y1ok) {
                    atomicAdd(&accH[b + 1], it.z * dx * dy1);
                    atomicAdd(&accV[b + 1], it.w * dx * dy1);
                }
            }
        }
    }
    __syncthreads();

    /* ---- y-scan: 8 rows x 512, row r handled by 128 threads x 4 elems ---- */
    int r   = tid >> 7;          /* 0..7 */
    int seg = tid & 127;         /* 0..127 */
    int b   = r * NB + seg * 4;
    accH[b + 1] += accH[b];  accH[b + 2] += accH[b + 1];  accH[b + 3] += accH[b + 2];
    accV[b + 1] += accV[b];  accV[b + 2] += accV[b + 1];  accV[b + 3] += accV[b + 2];
    __syncthreads();
#pragma unroll
    for (int o = 1; o < 128; o <<= 1) {
        float ph = 0.f, pv = 0.f;
        if (seg >= o) {
            int src = r * NB + (seg - o) * 4 + 3;
            ph = accH[src]; pv = accV[src];
        }
        __syncthreads();
        if (seg >= o) {
            int dst = r * NB + seg * 4 + 3;
            accH[dst] += ph; accV[dst] += pv;
        }
        __syncthreads();
    }
    {
        float eh = 0.f, ev = 0.f;
        if (seg > 0) {
            int src = r * NB + (seg - 1) * 4 + 3;
            eh = accH[src]; ev = accV[src];
        }
        accH[b] += eh; accH[b + 1] += eh; accH[b + 2] += eh;
        accV[b] += ev; accV[b + 1] += ev; accV[b + 2] += ev;
    }
    __syncthreads();

    /* ---- x-partial scan over the 8 rows + totals ---- */
    if (tid < NB) {
        int y = tid;
        float f = 0.f;
#pragma unroll
        for (int rr = 0; rr < SW; ++rr) {
            int i = rr * NB + y;
            f += accH[i]; accH[i] = f;
        }
        Th[st * NB + y] = f;
    } else if (tid < 2 * NB) {
        int y = tid - NB;
        float f = 0.f;
#pragma unroll
        for (int rr = 0; rr < SW; ++rr) {
            int i = rr * NB + y;
            f += accV[i]; accV[i] = f;
        }
        Tv[st * NB + y] = f;
    }
    __syncthreads();

    /* ---- dump scanned partials, coalesced ---- */
#pragma unroll
    for (int k = tid; k < SW * NB; k += 1024) {
        int rr = k >> 9, y = k & (NB - 1);
        int gi = (x0 + rr) * NB + y;
        UpH[gi] = accH[k];
        UpV[gi] = accV[k];
    }
}

// ---------------------------------------------------------------------------
// K_C: cross-stripe exclusive offsets + fused epilogue.
// ---------------------------------------------------------------------------
__global__ __launch_bounds__(512) void finish_kernel(
        const float* __restrict__ UpH, const float* __restrict__ UpV,
        const float* __restrict__ Th,  const float* __restrict__ Tv,
        float* __restrict__ out) {
    int st = blockIdx.x;
    int y  = threadIdx.x;
    float offh = 0.f, offv = 0.f;
    for (int s2 = 0; s2 < st; ++s2) {
        offh += Th[s2 * NB + y];
        offv += Tv[s2 * NB + y];
    }
#pragma unroll
    for (int rr = 0; rr < SW; ++rr) {
        int i = (st * SW + rr) * NB + y;
        float h = fabsf(UpH[i] + offh) * OUT_SCALE;
        float v = fabsf(UpV[i] + offv) * OUT_SCALE;
        float m = fmaxf(h, v);
        out[i] = fminf(fmaxf(m * m, 0.5f), 2.0f);
    }
}

// ---------------------------------------------------------------------------
// Fallback (tiny workspace): global-atomic scatter + scans (R0 pipeline)
// ---------------------------------------------------------------------------
__global__ void scatter_kernel(const float* __restrict__ pin_pos,
                               const int*   __restrict__ flat_netpin,
                               const float* __restrict__ net_weights,
                               float* __restrict__ Uh,
                               float* __restrict__ Uv) {
    int n = blockIdx.x * blockDim.x + threadIdx.x;
    if (n >= NUM_NETS) return;
    float xmn = 1e30f, xmx = -1e30f, ymn = 1e30f, ymx = -1e30f;
#pragma unroll
    for (int p = 0; p < PINS_PER_NET; ++p) {
        int pi  = flat_netpin[n * PINS_PER_NET + p];
        float x = pin_pos[pi];
        float y = pin_pos[NUM_PINS + pi];
        xmn = fminf(xmn, x); xmx = fmaxf(xmx, x);
        ymn = fminf(ymn, y); ymx = fmaxf(ymx, y);
    }
    float w  = net_weights[n];
    float wh = w / (ymx - ymn), wv = w / (xmx - xmn);
    int kx1 = min(NB - 1, (int)(xmn * INV_H));
    int kx2 = min(NB - 1, (int)(xmx * INV_H));
    int ky1 = min(NB - 1, (int)(ymn * INV_H));
    int ky2 = min(NB - 1, (int)(ymx * INV_H));
    int   xi[4] = { kx1, kx1 + 1, kx2, kx2 + 1 };
    float xv[4] = { (kx1 + 1) * BIN_H - xmn,  xmn - kx1 * BIN_H,
                    xmx - (kx2 + 1) * BIN_H,  kx2 * BIN_H - xmx };
    int   yi[4] = { ky1, ky1 + 1, ky2, ky2 + 1 };
    float yv[4] = { (ky1 + 1) * BIN_H - ymn,  ymn - ky1 * BIN_H,
                    ymx - (ky2 + 1) * BIN_H,  ky2 * BIN_H - ymx };
#pragma unroll
    for (int a = 0; a < 4; ++a) {
        if (xi[a] >= NB) continue;
#pragma unroll
        for (int b2 = 0; b2 < 4; ++b2) {
            if (yi[b2] >= NB) continue;
            float prod = xv[a] * yv[b2];
            atomicAdd(&Uh[xi[a] * NB + yi[b2]], wh * prod);
            atomicAdd(&Uv[xi[a] * NB + yi[b2]], wv * prod);
        }
    }
}

__global__ void row_scan_kernel(float* __restrict__ Uh, float* __restrict__ Uv) {
    __shared__ float sh[NB];
    __shared__ float sv[NB];
    int rr = blockIdx.x, t = threadIdx.x;
    sh[t] = Uh[rr * NB + t];
    sv[t] = Uv[rr * NB + t];
    __syncthreads();
#pragma unroll
    for (int off = 1; off < NB; off <<= 1) {
        float a = (t >= off) ? sh[t - off] : 0.0f;
        float b = (t >= off) ? sv[t - off] : 0.0f;
        __syncthreads();
        sh[t] += a; sv[t] += b;
        __syncthreads();
    }
    Uh[rr * NB + t] = sh[t];
    Uv[rr * NB + t] = sv[t];
}

__global__ void fb_colscan_kernel(const float* __restrict__ Uh,
                                  const float* __restrict__ Uv,
                                  float* __restrict__ out) {
    int t = blockIdx.x * blockDim.x + threadIdx.x;
    if (t >= NB) return;
    float sh = 0.f, sv = 0.f;
    for (int i = 0; i < NB; ++i) {
        sh += Uh[i * NB + t];
        sv += Uv[i * NB + t];
        float h = fabsf(sh) * OUT_SCALE;
        float v = fabsf(sv) * OUT_SCALE;
        float m = fmaxf(h, v);
        out[i * NB + t] = fminf(fmaxf(m * m, 0.5f), 2.0f);
    }
}

extern "C" void kernel_launch(void* const* d_in, const int* in_sizes, int n_in,
                              void* d_out, int out_size, void* d_ws, size_t ws_size,
                              hipStream_t stream) {
    const float* pin_pos     = (const float*)d_in[0];
    const int*   flat_netpin = (const int*)d_in[2];
    const float* net_weights = (const float*)d_in[3];
    float* out = (float*)d_out;
    float* ws  = (float*)d_ws;

    /* layout (floats): gcur[64] | bucket[64*CAP*4] | Th[64*512] | Tv[64*512]
                        | UpH[512*512] | UpV[512*512] */
    const size_t o_cur = 0;
    const size_t o_bkt = 64;                               /* 16B aligned */
    const size_t o_Th  = o_bkt + (size_t)NSTRIPES * CAP * 4;
    const size_t o_Tv  = o_Th + (size_t)NSTRIPES * NB;
    const size_t o_UpH = o_Tv + (size_t)NSTRIPES * NB;
    const size_t o_UpV = o_UpH + (size_t)NB * NB;
    const size_t need  = o_UpV + (size_t)NB * NB;

    if (ws_size < need * sizeof(float)) {
        /* fallback: global-atomic scatter pipeline */
        float* Uh = ws;
        float* Uv = ws + (size_t)NB * NB;
        hipMemsetAsync(ws, 0, 2 * (size_t)NB * NB * sizeof(float), stream);
        scatter_kernel<<<(NUM_NETS + 255) / 256, 256, 0, stream>>>(
            pin_pos, flat_netpin, net_weights, Uh, Uv);
        row_scan_kernel<<<NB, NB, 0, stream>>>(Uh, Uv);
        fb_colscan_kernel<<<2, 256, 0, stream>>>(Uh, Uv, out);
        return;
    }

    int*    gcur   = (int*)(ws + o_cur);
    float4* bucket = (float4*)(ws + o_bkt);
    float*  Th     = ws + o_Th;
    float*  Tv     = ws + o_Tv;
    float*  UpH    = ws + o_UpH;
    float*  UpV    = ws + o_UpV;

    hipMemsetAsync(gcur, 0, NSTRIPES * sizeof(int), stream);

    bbox_emit_kernel<<<(NUM_NETS + 255) / 256, 256, 0, stream>>>(
        pin_pos, flat_netpin, net_weights, gcur, bucket);

    stripe_kernel<<<NSTRIPES, 1024, 0, stream>>>(bucket, gcur, UpH, UpV, Th, Tv);

    finish_kernel<<<NSTRIPES, 512, 0, stream>>>(UpH, UpV, Th, Tv, out);
}

// Round 7
// 101.255 us; speedup vs baseline: 1.9350x; 1.9350x over previous
//
#include <hip/hip_runtime.h>

#define NUM_NETS     100000
#define PINS_PER_NET 5
#define NUM_PINS     (NUM_NETS * PINS_PER_NET)
#define NB           512
#define BIN_H        1.953125f          /* 1000/512, exact in fp32 */
#define INV_H        0.512f             /* 512/1000 */
#define OUT_SCALE    (1.0f / 195.3125f) /* 1/(BIN_SIZE_X * 100 tracks) */

#define SW           8                  /* stripe width (bins in x) */
#define NSTRIPES     (NB / SW)          /* 64 */
#define NSLICE       8                  /* y-slices per stripe */
#define SLH          (NB / NSLICE)      /* 64 bins per slice */
#define CAP          24576              /* items per stripe bucket (worst ~16K) */
#define STRIPE       8
#define NSTRIPE      (NB / STRIPE)      /* 64 */

// ---------------------------------------------------------------------------
// K_A: bbox + emit 16B items {x, y, s*wh, s*wv} into per-stripe buckets.
// (verified fast in R6 — unchanged)
// ---------------------------------------------------------------------------
__global__ __launch_bounds__(256) void bbox_emit_kernel(
        const float* __restrict__ pin_pos,
        const int*   __restrict__ flat_netpin,
        const float* __restrict__ net_weights,
        int* __restrict__ gcur,
        float4* __restrict__ bucket) {
    __shared__ int lcnt[NSTRIPES];
    __shared__ int lbase[NSTRIPES];
    int tid = threadIdx.x;
    if (tid < NSTRIPES) lcnt[tid] = 0;
    __syncthreads();

    int n = blockIdx.x * 256 + tid;
    bool valid = n < NUM_NETS;
    float xmn = 1e30f, xmx = -1e30f, ymn = 1e30f, ymx = -1e30f;
    float wh = 0.f, wv = 0.f;
    int kx1 = 0, kx2 = 0;
    if (valid) {
#pragma unroll
        for (int p = 0; p < PINS_PER_NET; ++p) {
            int pi  = flat_netpin[n * PINS_PER_NET + p];
            float x = pin_pos[pi];
            float y = pin_pos[NUM_PINS + pi];
            xmn = fminf(xmn, x); xmx = fmaxf(xmx, x);
            ymn = fminf(ymn, y); ymx = fmaxf(ymx, y);
        }
        float w = net_weights[n];
        wh = w / (ymx - ymn);
        wv = w / (xmx - xmn);
        kx1 = min(NB - 1, (int)(xmn * INV_H));
        kx2 = min(NB - 1, (int)(xmx * INV_H));
#pragma unroll
        for (int cx = 0; cx < 2; ++cx) {
            int kx = cx ? kx2 : kx1;
            int s0 = kx >> 3;
            atomicAdd(&lcnt[s0], 2);
            if (kx + 1 < NB && ((kx + 1) >> 3) != s0)
                atomicAdd(&lcnt[(kx + 1) >> 3], 2);
        }
    }
    __syncthreads();
    if (tid < NSTRIPES) {
        lbase[tid] = atomicAdd(&gcur[tid], lcnt[tid]);
        lcnt[tid] = 0;
    }
    __syncthreads();
    if (valid) {
#pragma unroll
        for (int cx = 0; cx < 2; ++cx) {
            int   kx = cx ? kx2 : kx1;
            float xc = cx ? xmx : xmn;
            int s0 = kx >> 3;
            int s1 = (kx + 1 < NB) ? ((kx + 1) >> 3) : s0;
#pragma unroll
            for (int cy = 0; cy < 2; ++cy) {
                float yc = cy ? ymx : ymn;
                float sg = ((cx ^ cy) ? -1.0f : 1.0f);
                float4 item = make_float4(xc, yc, sg * wh, sg * wv);
                {
                    int rank = atomicAdd(&lcnt[s0], 1);
                    int pos  = lbase[s0] + rank;
                    if (pos < CAP) bucket[(size_t)s0 * CAP + pos] = item;
                }
                if (s1 != s0) {
                    int rank = atomicAdd(&lcnt[s1], 1);
                    int pos  = lbase[s1] + rank;
                    if (pos < CAP) bucket[(size_t)s1 * CAP + pos] = item;
                }
            }
        }
    }
}

// ---------------------------------------------------------------------------
// K_B: fine-grained accumulation. Block = (stripe st, y-slice sl);
// 256 threads, 4KB LDS (2 x 8x64). Scans the whole stripe bucket, keeps
// only cells in its slice, writes its exclusive sub-tile to Uh/Uv.
// ---------------------------------------------------------------------------
__global__ __launch_bounds__(256) void accum_slice_kernel(
        const float4* __restrict__ bucket,
        const int* __restrict__ gcur,
        float* __restrict__ Uh, float* __restrict__ Uv) {
    __shared__ float accH[SW * SLH];    /* 2 KB */
    __shared__ float accV[SW * SLH];    /* 2 KB */
    int st = blockIdx.x >> 3;           /* stripe 0..63 */
    int sl = blockIdx.x & 7;            /* slice  0..7  */
    int x0 = st * SW;
    int y0 = sl * SLH;
    int tid = threadIdx.x;

    for (int k = tid; k < SW * SLH; k += 256) { accH[k] = 0.f; accV[k] = 0.f; }
    __syncthreads();

    int cnt = min(gcur[st], CAP);
    const float4* bk = bucket + (size_t)st * CAP;
    for (int q = tid; q < cnt; q += 256) {
        float4 it = bk[q];
        int kx = min(NB - 1, (int)(it.x * INV_H));
        int ky = min(NB - 1, (int)(it.y * INV_H));
        int gy = ky - y0;
        if ((unsigned)(gy + 1) > (unsigned)SLH) continue;  /* gy in [-1,64] */
        float dx0 = (kx + 1) * BIN_H - it.x;
        float dx1 = it.x - kx * BIN_H;
        float dy0 = (ky + 1) * BIN_H - it.y;
        float dy1 = it.y - ky * BIN_H;
        bool ok0 = (unsigned)gy < (unsigned)SLH;
        bool ok1 = ((unsigned)(gy + 1) < (unsigned)SLH) && (ky + 1 < NB);
        int c = kx - x0;
#pragma unroll
        for (int cc = 0; cc < 2; ++cc) {
            int col = c + cc;
            if ((unsigned)col < SW) {
                float dx = cc ? dx1 : dx0;
                int b = col * SLH + gy;
                if (ok0) {
                    atomicAdd(&accH[b], it.z * dx * dy0);
                    atomicAdd(&accV[b], it.w * dx * dy0);
                }
                if (ok1) {
                    atomicAdd(&accH[b + 1], it.z * dx * dy1);
                    atomicAdd(&accV[b + 1], it.w * dx * dy1);
                }
            }
        }
    }
    __syncthreads();

    for (int k = tid; k < SW * SLH; k += 256) {
        int col = k >> 6, y = k & (SLH - 1);
        int gi = (x0 + col) * NB + y0 + y;
        Uh[gi] = accH[k];
        Uv[gi] = accV[k];
    }
}

// ---------------------------------------------------------------------------
// K_C: inclusive y-scan per grid-row (shuffle). 512 blocks x 512 thr.
// ---------------------------------------------------------------------------
__global__ void rowscan_kernel(float* __restrict__ Uh, float* __restrict__ Uv) {
    __shared__ float swh[8], swv[8];
    int x = blockIdx.x, tid = threadIdx.x;
    int lane = tid & 63, wid = tid >> 6;
    float h = Uh[x * NB + tid];
    float v = Uv[x * NB + tid];
#pragma unroll
    for (int o = 1; o < 64; o <<= 1) {
        float a = __shfl_up(h, o);
        float b = __shfl_up(v, o);
        if (lane >= o) { h += a; v += b; }
    }
    if (lane == 63) { swh[wid] = h; swv[wid] = v; }
    __syncthreads();
    float oh = 0.f, ov = 0.f;
    for (int j = 0; j < wid; ++j) { oh += swh[j]; ov += swv[j]; }
    Uh[x * NB + tid] = h + oh;
    Uv[x * NB + tid] = v + ov;
}

// ---------------------------------------------------------------------------
// K_D: per-stripe partial column scans + totals (2D grid over columns)
// ---------------------------------------------------------------------------
__global__ void colscan_partial_kernel(float* __restrict__ Uh,
                                       float* __restrict__ Uv,
                                       float* __restrict__ totH,
                                       float* __restrict__ totV) {
    int s = blockIdx.x;
    int t = blockIdx.y * blockDim.x + threadIdx.x;
    float h = 0.f, v = 0.f;
#pragma unroll
    for (int i = 0; i < STRIPE; ++i) {
        int row = s * STRIPE + i;
        h += Uh[row * NB + t];  Uh[row * NB + t] = h;
        v += Uv[row * NB + t];  Uv[row * NB + t] = v;
    }
    totH[s * NB + t] = h;
    totV[s * NB + t] = v;
}

// ---------------------------------------------------------------------------
// K_E: stripe offsets + fused epilogue
// ---------------------------------------------------------------------------
__global__ void colscan_finish_kernel(const float* __restrict__ Uh,
                                      const float* __restrict__ Uv,
                                      const float* __restrict__ totH,
                                      const float* __restrict__ totV,
                                      float* __restrict__ out) {
    int s = blockIdx.x;
    int t = blockIdx.y * blockDim.x + threadIdx.x;
    float offh = 0.f, offv = 0.f;
    for (int s2 = 0; s2 < s; ++s2) {
        offh += totH[s2 * NB + t];
        offv += totV[s2 * NB + t];
    }
#pragma unroll
    for (int i = 0; i < STRIPE; ++i) {
        int row = s * STRIPE + i;
        float h = fabsf(Uh[row * NB + t] + offh) * OUT_SCALE;
        float v = fabsf(Uv[row * NB + t] + offv) * OUT_SCALE;
        float m = fmaxf(h, v);
        out[row * NB + t] = fminf(fmaxf(m * m, 0.5f), 2.0f);
    }
}

// ---------------------------------------------------------------------------
// Fallback (tiny workspace): global-atomic scatter + scans
// ---------------------------------------------------------------------------
__global__ void scatter_kernel(const float* __restrict__ pin_pos,
                               const int*   __restrict__ flat_netpin,
                               const float* __restrict__ net_weights,
                               float* __restrict__ Uh,
                               float* __restrict__ Uv) {
    int n = blockIdx.x * blockDim.x + threadIdx.x;
    if (n >= NUM_NETS) return;
    float xmn = 1e30f, xmx = -1e30f, ymn = 1e30f, ymx = -1e30f;
#pragma unroll
    for (int p = 0; p < PINS_PER_NET; ++p) {
        int pi  = flat_netpin[n * PINS_PER_NET + p];
        float x = pin_pos[pi];
        float y = pin_pos[NUM_PINS + pi];
        xmn = fminf(xmn, x); xmx = fmaxf(xmx, x);
        ymn = fminf(ymn, y); ymx = fmaxf(ymx, y);
    }
    float w  = net_weights[n];
    float wh = w / (ymx - ymn), wv = w / (xmx - xmn);
    int kx1 = min(NB - 1, (int)(xmn * INV_H));
    int kx2 = min(NB - 1, (int)(xmx * INV_H));
    int ky1 = min(NB - 1, (int)(ymn * INV_H));
    int ky2 = min(NB - 1, (int)(ymx * INV_H));
    int   xi[4] = { kx1, kx1 + 1, kx2, kx2 + 1 };
    float xv[4] = { (kx1 + 1) * BIN_H - xmn,  xmn - kx1 * BIN_H,
                    xmx - (kx2 + 1) * BIN_H,  kx2 * BIN_H - xmx };
    int   yi[4] = { ky1, ky1 + 1, ky2, ky2 + 1 };
    float yv[4] = { (ky1 + 1) * BIN_H - ymn,  ymn - ky1 * BIN_H,
                    ymx - (ky2 + 1) * BIN_H,  ky2 * BIN_H - ymx };
#pragma unroll
    for (int a = 0; a < 4; ++a) {
        if (xi[a] >= NB) continue;
#pragma unroll
        for (int b2 = 0; b2 < 4; ++b2) {
            if (yi[b2] >= NB) continue;
            float prod = xv[a] * yv[b2];
            atomicAdd(&Uh[xi[a] * NB + yi[b2]], wh * prod);
            atomicAdd(&Uv[xi[a] * NB + yi[b2]], wv * prod);
        }
    }
}

__global__ void fb_rowscan_kernel(float* __restrict__ Uh, float* __restrict__ Uv) {
    __shared__ float sh[NB];
    __shared__ float sv[NB];
    int rr = blockIdx.x, t = threadIdx.x;
    sh[t] = Uh[rr * NB + t];
    sv[t] = Uv[rr * NB + t];
    __syncthreads();
#pragma unroll
    for (int off = 1; off < NB; off <<= 1) {
        float a = (t >= off) ? sh[t - off] : 0.0f;
        float b = (t >= off) ? sv[t - off] : 0.0f;
        __syncthreads();
        sh[t] += a; sv[t] += b;
        __syncthreads();
    }
    Uh[rr * NB + t] = sh[t];
    Uv[rr * NB + t] = sv[t];
}

__global__ void fb_colscan_kernel(const float* __restrict__ Uh,
                                  const float* __restrict__ Uv,
                                  float* __restrict__ out) {
    int t = blockIdx.x * blockDim.x + threadIdx.x;
    if (t >= NB) return;
    float sh = 0.f, sv = 0.f;
    for (int i = 0; i < NB; ++i) {
        sh += Uh[i * NB + t];
        sv += Uv[i * NB + t];
        float h = fabsf(sh) * OUT_SCALE;
        float v = fabsf(sv) * OUT_SCALE;
        float m = fmaxf(h, v);
        out[i * NB + t] = fminf(fmaxf(m * m, 0.5f), 2.0f);
    }
}

extern "C" void kernel_launch(void* const* d_in, const int* in_sizes, int n_in,
                              void* d_out, int out_size, void* d_ws, size_t ws_size,
                              hipStream_t stream) {
    const float* pin_pos     = (const float*)d_in[0];
    const int*   flat_netpin = (const int*)d_in[2];
    const float* net_weights = (const float*)d_in[3];
    float* out = (float*)d_out;
    float* ws  = (float*)d_ws;

    /* layout (floats): gcur[64] | bucket[64*CAP*4] | Th[64*512] | Tv[64*512]
                        | Uh[512*512] | Uv[512*512] */
    const size_t o_cur = 0;
    const size_t o_bkt = 64;                               /* 16B aligned */
    const size_t o_Th  = o_bkt + (size_t)NSTRIPES * CAP * 4;
    const size_t o_Tv  = o_Th + (size_t)NSTRIPE * NB;
    const size_t o_Uh  = o_Tv + (size_t)NSTRIPE * NB;
    const size_t o_Uv  = o_Uh + (size_t)NB * NB;
    const size_t need  = o_Uv + (size_t)NB * NB;

    if (ws_size < need * sizeof(float)) {
        float* Uh = ws;
        float* Uv = ws + (size_t)NB * NB;
        hipMemsetAsync(ws, 0, 2 * (size_t)NB * NB * sizeof(float), stream);
        scatter_kernel<<<(NUM_NETS + 255) / 256, 256, 0, stream>>>(
            pin_pos, flat_netpin, net_weights, Uh, Uv);
        fb_rowscan_kernel<<<NB, NB, 0, stream>>>(Uh, Uv);
        fb_colscan_kernel<<<2, 256, 0, stream>>>(Uh, Uv, out);
        return;
    }

    int*    gcur   = (int*)(ws + o_cur);
    float4* bucket = (float4*)(ws + o_bkt);
    float*  Th     = ws + o_Th;
    float*  Tv     = ws + o_Tv;
    float*  Uh     = ws + o_Uh;
    float*  Uv     = ws + o_Uv;

    hipMemsetAsync(gcur, 0, NSTRIPES * sizeof(int), stream);

    bbox_emit_kernel<<<(NUM_NETS + 255) / 256, 256, 0, stream>>>(
        pin_pos, flat_netpin, net_weights, gcur, bucket);

    accum_slice_kernel<<<NSTRIPES * NSLICE, 256, 0, stream>>>(bucket, gcur, Uh, Uv);

    rowscan_kernel<<<NB, NB, 0, stream>>>(Uh, Uv);

    colscan_partial_kernel<<<dim3(NSTRIPE, 4), 128, 0, stream>>>(Uh, Uv, Th, Tv);

    colscan_finish_kernel<<<dim3(NSTRIPE, 4), 128, 0, stream>>>(Uh, Uv, Th, Tv, out);
}

// Round 8
// 101.215 us; speedup vs baseline: 1.9358x; 1.0004x over previous
//
#include <hip/hip_runtime.h>

#define NUM_NETS     100000
#define PINS_PER_NET 5
#define NUM_PINS     (NUM_NETS * PINS_PER_NET)
#define NB           512
#define BIN_H        1.953125f          /* 1000/512, exact in fp32 */
#define INV_H        0.512f             /* 512/1000 */
#define OUT_SCALE    (1.0f / 195.3125f) /* 1/(BIN_SIZE_X * 100 tracks) */

#define SW           8                  /* stripe width (x bins) */
#define NSTRIPES     (NB / SW)          /* 64 */
#define NSLICE       8                  /* y slices */
#define SLH          (NB / NSLICE)      /* 64 */
#define NBUCKET      (NSTRIPES * NSLICE)/* 512 */
#define NBLK         ((NUM_NETS + 1023) / 1024)  /* 98 */
#define ITEMS_MAX    1048576            /* 16 MB of float4; actual ~0.5M */
#define STRIPE       8
#define NSTRIPE      (NB / STRIPE)      /* 64 */

// bucket id for cluster cell (kx,ky): stripe kx>>3, slice ky>>6
template <class F>
__device__ __forceinline__ void for_each_bucket(int kx, int ky, F&& f) {
    int s0 = kx >> 3, t0 = ky >> 6;
    int s1 = (kx + 1 < NB && ((kx + 1) >> 3) != s0) ? ((kx + 1) >> 3) : -1;
    int t1 = (ky + 1 < NB && ((ky + 1) >> 6) != t0) ? ((ky + 1) >> 6) : -1;
    f(s0 * NSLICE + t0);
    if (s1 >= 0)            f(s1 * NSLICE + t0);
    if (t1 >= 0)            f(s0 * NSLICE + t1);
    if (s1 >= 0 && t1 >= 0) f(s1 * NSLICE + t1);
}

// ---------------------------------------------------------------------------
// A: gather pins once -> bbox records + per-block bucket counts.
//   recA[n] = {xmn,xmx,ymn,ymx}; recB[n] = {wh,wv,pack(kx1,kx2),pack(ky1,ky2)}
// ---------------------------------------------------------------------------
__global__ __launch_bounds__(1024) void bbox_count_kernel(
        const float* __restrict__ pin_pos,
        const int*   __restrict__ flat_netpin,
        const float* __restrict__ net_weights,
        float4* __restrict__ recA, float4* __restrict__ recB,
        int* __restrict__ pcount) {
    __shared__ int lcnt[NBUCKET];
    int tid = threadIdx.x;
    if (tid < NBUCKET) lcnt[tid] = 0;
    __syncthreads();

    int n = blockIdx.x * 1024 + tid;
    if (n < NUM_NETS) {
        float xmn = 1e30f, xmx = -1e30f, ymn = 1e30f, ymx = -1e30f;
#pragma unroll
        for (int p = 0; p < PINS_PER_NET; ++p) {
            int pi  = flat_netpin[n * PINS_PER_NET + p];
            float x = pin_pos[pi];
            float y = pin_pos[NUM_PINS + pi];
            xmn = fminf(xmn, x); xmx = fmaxf(xmx, x);
            ymn = fminf(ymn, y); ymx = fmaxf(ymx, y);
        }
        float w = net_weights[n];
        int kx1 = min(NB - 1, (int)(xmn * INV_H));
        int kx2 = min(NB - 1, (int)(xmx * INV_H));
        int ky1 = min(NB - 1, (int)(ymn * INV_H));
        int ky2 = min(NB - 1, (int)(ymx * INV_H));
        recA[n] = make_float4(xmn, xmx, ymn, ymx);
        recB[n] = make_float4(w / (ymx - ymn), w / (xmx - xmn),
                              __uint_as_float((unsigned)kx1 | ((unsigned)kx2 << 16)),
                              __uint_as_float((unsigned)ky1 | ((unsigned)ky2 << 16)));
#pragma unroll
        for (int cx = 0; cx < 2; ++cx) {
            int kx = cx ? kx2 : kx1;
#pragma unroll
            for (int cy = 0; cy < 2; ++cy) {
                int ky = cy ? ky2 : ky1;
                for_each_bucket(kx, ky, [&](int b) { atomicAdd(&lcnt[b], 1); });
            }
        }
    }
    __syncthreads();
    if (tid < NBUCKET) pcount[blockIdx.x * NBUCKET + tid] = lcnt[tid];
}

// ---------------------------------------------------------------------------
// B: bucket totals + exclusive offsets + cursor init (1 block, 512 thr)
// ---------------------------------------------------------------------------
__global__ __launch_bounds__(512) void offsets_kernel(
        const int* __restrict__ pcount,
        int* __restrict__ gcnt, int* __restrict__ goff, int* __restrict__ gcur) {
    __shared__ int wsum[8];
    int t = threadIdx.x;
    int c = 0;
    for (int b = 0; b < NBLK; ++b) c += pcount[b * NBUCKET + t];
    int lane = t & 63, wid = t >> 6;
    int inc = c;
#pragma unroll
    for (int o = 1; o < 64; o <<= 1) {
        int a = __shfl_up(inc, o);
        if (lane >= o) inc += a;
    }
    if (lane == 63) wsum[wid] = inc;
    __syncthreads();
    int off = 0;
    for (int j = 0; j < wid; ++j) off += wsum[j];
    int excl = off + inc - c;
    gcnt[t] = c;
    goff[t] = excl;
    gcur[t] = excl;
}

// ---------------------------------------------------------------------------
// C: emit items {x,y,±wh,±wv} into exact per-bucket segments (reads rec only)
// ---------------------------------------------------------------------------
__global__ __launch_bounds__(1024) void emit_kernel(
        const float4* __restrict__ recA, const float4* __restrict__ recB,
        int* __restrict__ gcur, float4* __restrict__ items) {
    __shared__ int lcnt[NBUCKET];
    __shared__ int lbase[NBUCKET];
    int tid = threadIdx.x;
    if (tid < NBUCKET) lcnt[tid] = 0;
    __syncthreads();

    int n = blockIdx.x * 1024 + tid;
    bool valid = n < NUM_NETS;
    float4 ra, rb;
    int kx1 = 0, kx2 = 0, ky1 = 0, ky2 = 0;
    if (valid) {
        ra = recA[n]; rb = recB[n];
        unsigned pkx = __float_as_uint(rb.z), pky = __float_as_uint(rb.w);
        kx1 = (int)(pkx & 0xffffu); kx2 = (int)(pkx >> 16);
        ky1 = (int)(pky & 0xffffu); ky2 = (int)(pky >> 16);
#pragma unroll
        for (int cx = 0; cx < 2; ++cx) {
            int kx = cx ? kx2 : kx1;
#pragma unroll
            for (int cy = 0; cy < 2; ++cy) {
                int ky = cy ? ky2 : ky1;
                for_each_bucket(kx, ky, [&](int b) { atomicAdd(&lcnt[b], 1); });
            }
        }
    }
    __syncthreads();
    if (tid < NBUCKET) {
        lbase[tid] = atomicAdd(&gcur[tid], lcnt[tid]);
        lcnt[tid] = 0;
    }
    __syncthreads();
    if (valid) {
        float xmn = ra.x, xmx = ra.y, ymn = ra.z, ymx = ra.w;
        float wh = rb.x, wv = rb.y;
#pragma unroll
        for (int cx = 0; cx < 2; ++cx) {
            int   kx = cx ? kx2 : kx1;
            float xc = cx ? xmx : xmn;
#pragma unroll
            for (int cy = 0; cy < 2; ++cy) {
                int   ky = cy ? ky2 : ky1;
                float yc = cy ? ymx : ymn;
                float sg = (cx ^ cy) ? -1.0f : 1.0f;
                float4 item = make_float4(xc, yc, sg * wh, sg * wv);
                for_each_bucket(kx, ky, [&](int b) {
                    int rank = atomicAdd(&lcnt[b], 1);
                    int pos  = lbase[b] + rank;
                    if (pos < ITEMS_MAX) items[pos] = item;
                });
            }
        }
    }
}

// ---------------------------------------------------------------------------
// D: per-bucket accumulate into exclusive 8x64 sub-tile. 512 blocks x 256.
// ---------------------------------------------------------------------------
__global__ __launch_bounds__(256) void accum_kernel(
        const float4* __restrict__ items,
        const int* __restrict__ gcnt, const int* __restrict__ goff,
        float* __restrict__ Uh, float* __restrict__ Uv) {
    __shared__ float accH[SW * SLH];    /* 2 KB */
    __shared__ float accV[SW * SLH];    /* 2 KB */
    int b  = blockIdx.x;
    int st = b >> 3, sl = b & 7;
    int x0 = st * SW, y0 = sl * SLH;
    int tid = threadIdx.x;

    for (int k = tid; k < SW * SLH; k += 256) { accH[k] = 0.f; accV[k] = 0.f; }
    __syncthreads();

    int i0  = goff[b];
    int end = min(i0 + gcnt[b], ITEMS_MAX);
    for (int q = i0 + tid; q < end; q += 256) {
        float4 it = items[q];
        int kx = min(NB - 1, (int)(it.x * INV_H));
        int ky = min(NB - 1, (int)(it.y * INV_H));
        float dx0 = (kx + 1) * BIN_H - it.x;
        float dx1 = it.x - kx * BIN_H;
        float dy0 = (ky + 1) * BIN_H - it.y;
        float dy1 = it.y - ky * BIN_H;
        int gy = ky - y0;
        bool ok0 = (unsigned)gy < (unsigned)SLH;
        bool ok1 = ((unsigned)(gy + 1) < (unsigned)SLH) && (ky + 1 < NB);
        int c = kx - x0;
#pragma unroll
        for (int cc = 0; cc < 2; ++cc) {
            int col = c + cc;
            if ((unsigned)col < SW) {
                float dx = cc ? dx1 : dx0;
                if (ok0) {
                    int i = col * SLH + gy;
                    atomicAdd(&accH[i], it.z * dx * dy0);
                    atomicAdd(&accV[i], it.w * dx * dy0);
                }
                if (ok1) {
                    int i = col * SLH + gy + 1;
                    atomicAdd(&accH[i], it.z * dx * dy1);
                    atomicAdd(&accV[i], it.w * dx * dy1);
                }
            }
        }
    }
    __syncthreads();

    for (int k = tid; k < SW * SLH; k += 256) {
        int col = k >> 6, y = k & (SLH - 1);
        int gi = (x0 + col) * NB + y0 + y;
        Uh[gi] = accH[k];
        Uv[gi] = accV[k];
    }
}

// ---------------------------------------------------------------------------
// E: inclusive y-scan per grid-row (shuffle). 512 blocks x 512 thr.
// ---------------------------------------------------------------------------
__global__ void rowscan_kernel(float* __restrict__ Uh, float* __restrict__ Uv) {
    __shared__ float swh[8], swv[8];
    int x = blockIdx.x, tid = threadIdx.x;
    int lane = tid & 63, wid = tid >> 6;
    float h = Uh[x * NB + tid];
    float v = Uv[x * NB + tid];
#pragma unroll
    for (int o = 1; o < 64; o <<= 1) {
        float a = __shfl_up(h, o);
        float b = __shfl_up(v, o);
        if (lane >= o) { h += a; v += b; }
    }
    if (lane == 63) { swh[wid] = h; swv[wid] = v; }
    __syncthreads();
    float oh = 0.f, ov = 0.f;
    for (int j = 0; j < wid; ++j) { oh += swh[j]; ov += swv[j]; }
    Uh[x * NB + tid] = h + oh;
    Uv[x * NB + tid] = v + ov;
}

// ---------------------------------------------------------------------------
// F: per-stripe partial column scans + totals
// ---------------------------------------------------------------------------
__global__ void colscan_partial_kernel(float* __restrict__ Uh,
                                       float* __restrict__ Uv,
                                       float* __restrict__ totH,
                                       float* __restrict__ totV) {
    int s = blockIdx.x;
    int t = blockIdx.y * blockDim.x + threadIdx.x;
    float h = 0.f, v = 0.f;
#pragma unroll
    for (int i = 0; i < STRIPE; ++i) {
        int row = s * STRIPE + i;
        h += Uh[row * NB + t];  Uh[row * NB + t] = h;
        v += Uv[row * NB + t];  Uv[row * NB + t] = v;
    }
    totH[s * NB + t] = h;
    totV[s * NB + t] = v;
}

// ---------------------------------------------------------------------------
// G: stripe offsets + fused epilogue
// ---------------------------------------------------------------------------
__global__ void colscan_finish_kernel(const float* __restrict__ Uh,
                                      const float* __restrict__ Uv,
                                      const float* __restrict__ totH,
                                      const float* __restrict__ totV,
                                      float* __restrict__ out) {
    int s = blockIdx.x;
    int t = blockIdx.y * blockDim.x + threadIdx.x;
    float offh = 0.f, offv = 0.f;
    for (int s2 = 0; s2 < s; ++s2) {
        offh += totH[s2 * NB + t];
        offv += totV[s2 * NB + t];
    }
#pragma unroll
    for (int i = 0; i < STRIPE; ++i) {
        int row = s * STRIPE + i;
        float h = fabsf(Uh[row * NB + t] + offh) * OUT_SCALE;
        float v = fabsf(Uv[row * NB + t] + offv) * OUT_SCALE;
        float m = fmaxf(h, v);
        out[row * NB + t] = fminf(fmaxf(m * m, 0.5f), 2.0f);
    }
}

// ---------------------------------------------------------------------------
// Fallback (tiny workspace): global-atomic scatter + scans
// ---------------------------------------------------------------------------
__global__ void scatter_kernel(const float* __restrict__ pin_pos,
                               const int*   __restrict__ flat_netpin,
                               const float* __restrict__ net_weights,
                               float* __restrict__ Uh,
                               float* __restrict__ Uv) {
    int n = blockIdx.x * blockDim.x + threadIdx.x;
    if (n >= NUM_NETS) return;
    float xmn = 1e30f, xmx = -1e30f, ymn = 1e30f, ymx = -1e30f;
#pragma unroll
    for (int p = 0; p < PINS_PER_NET; ++p) {
        int pi  = flat_netpin[n * PINS_PER_NET + p];
        float x = pin_pos[pi];
        float y = pin_pos[NUM_PINS + pi];
        xmn = fminf(xmn, x); xmx = fmaxf(xmx, x);
        ymn = fminf(ymn, y); ymx = fmaxf(ymx, y);
    }
    float w  = net_weights[n];
    float wh = w / (ymx - ymn), wv = w / (xmx - xmn);
    int kx1 = min(NB - 1, (int)(xmn * INV_H));
    int kx2 = min(NB - 1, (int)(xmx * INV_H));
    int ky1 = min(NB - 1, (int)(ymn * INV_H));
    int ky2 = min(NB - 1, (int)(ymx * INV_H));
    int   xi[4] = { kx1, kx1 + 1, kx2, kx2 + 1 };
    float xv[4] = { (kx1 + 1) * BIN_H - xmn,  xmn - kx1 * BIN_H,
                    xmx - (kx2 + 1) * BIN_H,  kx2 * BIN_H - xmx };
    int   yi[4] = { ky1, ky1 + 1, ky2, ky2 + 1 };
    float yv[4] = { (ky1 + 1) * BIN_H - ymn,  ymn - ky1 * BIN_H,
                    ymx - (ky2 + 1) * BIN_H,  ky2 * BIN_H - ymx };
#pragma unroll
    for (int a = 0; a < 4; ++a) {
        if (xi[a] >= NB) continue;
#pragma unroll
        for (int b2 = 0; b2 < 4; ++b2) {
            if (yi[b2] >= NB) continue;
            float prod = xv[a] * yv[b2];
            atomicAdd(&Uh[xi[a] * NB + yi[b2]], wh * prod);
            atomicAdd(&Uv[xi[a] * NB + yi[b2]], wv * prod);
        }
    }
}

__global__ void fb_rowscan_kernel(float* __restrict__ Uh, float* __restrict__ Uv) {
    __shared__ float sh[NB];
    __shared__ float sv[NB];
    int rr = blockIdx.x, t = threadIdx.x;
    sh[t] = Uh[rr * NB + t];
    sv[t] = Uv[rr * NB + t];
    __syncthreads();
#pragma unroll
    for (int off = 1; off < NB; off <<= 1) {
        float a = (t >= off) ? sh[t - off] : 0.0f;
        float b = (t >= off) ? sv[t - off] : 0.0f;
        __syncthreads();
        sh[t] += a; sv[t] += b;
        __syncthreads();
    }
    Uh[rr * NB + t] = sh[t];
    Uv[rr * NB + t] = sv[t];
}

__global__ void fb_colscan_kernel(const float* __restrict__ Uh,
                                  const float* __restrict__ Uv,
                                  float* __restrict__ out) {
    int t = blockIdx.x * blockDim.x + threadIdx.x;
    if (t >= NB) return;
    float sh = 0.f, sv = 0.f;
    for (int i = 0; i < NB; ++i) {
        sh += Uh[i * NB + t];
        sv += Uv[i * NB + t];
        float h = fabsf(sh) * OUT_SCALE;
        float v = fabsf(sv) * OUT_SCALE;
        float m = fmaxf(h, v);
        out[i * NB + t] = fminf(fmaxf(m * m, 0.5f), 2.0f);
    }
}

extern "C" void kernel_launch(void* const* d_in, const int* in_sizes, int n_in,
                              void* d_out, int out_size, void* d_ws, size_t ws_size,
                              hipStream_t stream) {
    const float* pin_pos     = (const float*)d_in[0];
    const int*   flat_netpin = (const int*)d_in[2];
    const float* net_weights = (const float*)d_in[3];
    float* out = (float*)d_out;
    float* ws  = (float*)d_ws;

    /* layout (floats):
       recA[400K] recB[400K] pcount[NBLK*512] gcnt[512] goff[512] gcur[512]
       items[ITEMS_MAX*4] Uh[256K] Uv[256K] Th[32K] Tv[32K]        (~22.5 MB) */
    const size_t o_recA = 0;
    const size_t o_recB = o_recA + (size_t)NUM_NETS * 4;
    const size_t o_pcnt = o_recB + (size_t)NUM_NETS * 4;
    const size_t o_gcnt = o_pcnt + (size_t)NBLK * NBUCKET;
    const size_t o_goff = o_gcnt + NBUCKET;
    const size_t o_gcur = o_goff + NBUCKET;
    const size_t o_itm  = (o_gcur + NBUCKET + 3) & ~(size_t)3;
    const size_t o_Uh   = o_itm + (size_t)ITEMS_MAX * 4;
    const size_t o_Uv   = o_Uh + (size_t)NB * NB;
    const size_t o_Th   = o_Uv + (size_t)NB * NB;
    const size_t o_Tv   = o_Th + (size_t)NSTRIPE * NB;
    const size_t need   = o_Tv + (size_t)NSTRIPE * NB;

    if (ws_size < need * sizeof(float)) {
        float* Uh = ws;
        float* Uv = ws + (size_t)NB * NB;
        hipMemsetAsync(ws, 0, 2 * (size_t)NB * NB * sizeof(float), stream);
        scatter_kernel<<<(NUM_NETS + 255) / 256, 256, 0, stream>>>(
            pin_pos, flat_netpin, net_weights, Uh, Uv);
        fb_rowscan_kernel<<<NB, NB, 0, stream>>>(Uh, Uv);
        fb_colscan_kernel<<<2, 256, 0, stream>>>(Uh, Uv, out);
        return;
    }

    float4* recA  = (float4*)(ws + o_recA);
    float4* recB  = (float4*)(ws + o_recB);
    int*    pcnt  = (int*)(ws + o_pcnt);
    int*    gcnt  = (int*)(ws + o_gcnt);
    int*    goff  = (int*)(ws + o_goff);
    int*    gcur  = (int*)(ws + o_gcur);
    float4* items = (float4*)(ws + o_itm);
    float*  Uh    = ws + o_Uh;
    float*  Uv    = ws + o_Uv;
    float*  Th    = ws + o_Th;
    float*  Tv    = ws + o_Tv;

    bbox_count_kernel<<<NBLK, 1024, 0, stream>>>(
        pin_pos, flat_netpin, net_weights, recA, recB, pcnt);

    offsets_kernel<<<1, 512, 0, stream>>>(pcnt, gcnt, goff, gcur);

    emit_kernel<<<NBLK, 1024, 0, stream>>>(recA, recB, gcur, items);

    accum_kernel<<<NBUCKET, 256, 0, stream>>>(items, gcnt, goff, Uh, Uv);

    rowscan_kernel<<<NB, NB, 0, stream>>>(Uh, Uv);

    colscan_partial_kernel<<<dim3(NSTRIPE, 4), 128, 0, stream>>>(Uh, Uv, Th, Tv);

    colscan_finish_kernel<<<dim3(NSTRIPE, 4), 128, 0, stream>>>(Uh, Uv, Th, Tv, out);
}

// Round 9
// 101.068 us; speedup vs baseline: 1.9386x; 1.0015x over previous
//
#include <hip/hip_runtime.h>

#define NUM_NETS     100000
#define PINS_PER_NET 5
#define NUM_PINS     (NUM_NETS * PINS_PER_NET)
#define NB           512
#define BIN_H        1.953125f          /* 1000/512, exact in fp32 */
#define INV_H        0.512f             /* 512/1000 */
#define OUT_SCALE    (1.0f / 195.3125f) /* 1/(BIN_SIZE_X * 100 tracks) */

#define SW           8                  /* stripe width (x bins) */
#define NSTRIPES     (NB / SW)          /* 64 */
#define NSLICE       8                  /* y slices */
#define SLH          (NB / NSLICE)      /* 64 */
#define NBUCKET      (NSTRIPES * NSLICE)/* 512 */
#define NBLK         ((NUM_NETS + 1023) / 1024)  /* 98 */
#define ITEMS_MAX    1048576            /* 16 MB of float4; actual ~0.5M */
#define STRIPE       8
#define NSTRIPE      (NB / STRIPE)      /* 64 */
#define UNROLL       8                  /* accum MLP depth */

// bucket id for cluster cell (kx,ky): stripe kx>>3, slice ky>>6
template <class F>
__device__ __forceinline__ void for_each_bucket(int kx, int ky, F&& f) {
    int s0 = kx >> 3, t0 = ky >> 6;
    int s1 = (kx + 1 < NB && ((kx + 1) >> 3) != s0) ? ((kx + 1) >> 3) : -1;
    int t1 = (ky + 1 < NB && ((ky + 1) >> 6) != t0) ? ((ky + 1) >> 6) : -1;
    f(s0 * NSLICE + t0);
    if (s1 >= 0)            f(s1 * NSLICE + t0);
    if (t1 >= 0)            f(s0 * NSLICE + t1);
    if (s1 >= 0 && t1 >= 0) f(s1 * NSLICE + t1);
}

// ---------------------------------------------------------------------------
// A: gather pins once -> bbox records + per-block bucket counts.
// ---------------------------------------------------------------------------
__global__ __launch_bounds__(1024) void bbox_count_kernel(
        const float* __restrict__ pin_pos,
        const int*   __restrict__ flat_netpin,
        const float* __restrict__ net_weights,
        float4* __restrict__ recA, float4* __restrict__ recB,
        int* __restrict__ pcount) {
    __shared__ int lcnt[NBUCKET];
    int tid = threadIdx.x;
    if (tid < NBUCKET) lcnt[tid] = 0;
    __syncthreads();

    int n = blockIdx.x * 1024 + tid;
    if (n < NUM_NETS) {
        float xmn = 1e30f, xmx = -1e30f, ymn = 1e30f, ymx = -1e30f;
#pragma unroll
        for (int p = 0; p < PINS_PER_NET; ++p) {
            int pi  = flat_netpin[n * PINS_PER_NET + p];
            float x = pin_pos[pi];
            float y = pin_pos[NUM_PINS + pi];
            xmn = fminf(xmn, x); xmx = fmaxf(xmx, x);
            ymn = fminf(ymn, y); ymx = fmaxf(ymx, y);
        }
        float w = net_weights[n];
        int kx1 = min(NB - 1, (int)(xmn * INV_H));
        int kx2 = min(NB - 1, (int)(xmx * INV_H));
        int ky1 = min(NB - 1, (int)(ymn * INV_H));
        int ky2 = min(NB - 1, (int)(ymx * INV_H));
        recA[n] = make_float4(xmn, xmx, ymn, ymx);
        recB[n] = make_float4(w / (ymx - ymn), w / (xmx - xmn),
                              __uint_as_float((unsigned)kx1 | ((unsigned)kx2 << 16)),
                              __uint_as_float((unsigned)ky1 | ((unsigned)ky2 << 16)));
#pragma unroll
        for (int cx = 0; cx < 2; ++cx) {
            int kx = cx ? kx2 : kx1;
#pragma unroll
            for (int cy = 0; cy < 2; ++cy) {
                int ky = cy ? ky2 : ky1;
                for_each_bucket(kx, ky, [&](int b) { atomicAdd(&lcnt[b], 1); });
            }
        }
    }
    __syncthreads();
    if (tid < NBUCKET) pcount[blockIdx.x * NBUCKET + tid] = lcnt[tid];
}

// ---------------------------------------------------------------------------
// B: bucket totals + exclusive offsets + cursor init (1 block, 512 thr)
// ---------------------------------------------------------------------------
__global__ __launch_bounds__(512) void offsets_kernel(
        const int* __restrict__ pcount,
        int* __restrict__ gcnt, int* __restrict__ goff, int* __restrict__ gcur) {
    __shared__ int wsum[8];
    int t = threadIdx.x;
    int c = 0;
    for (int b = 0; b < NBLK; ++b) c += pcount[b * NBUCKET + t];
    int lane = t & 63, wid = t >> 6;
    int inc = c;
#pragma unroll
    for (int o = 1; o < 64; o <<= 1) {
        int a = __shfl_up(inc, o);
        if (lane >= o) inc += a;
    }
    if (lane == 63) wsum[wid] = inc;
    __syncthreads();
    int off = 0;
    for (int j = 0; j < wid; ++j) off += wsum[j];
    int excl = off + inc - c;
    gcnt[t] = c;
    goff[t] = excl;
    gcur[t] = excl;
}

// ---------------------------------------------------------------------------
// C: emit items {x,y,±wh,±wv} into exact per-bucket segments
// ---------------------------------------------------------------------------
__global__ __launch_bounds__(1024) void emit_kernel(
        const float4* __restrict__ recA, const float4* __restrict__ recB,
        int* __restrict__ gcur, float4* __restrict__ items) {
    __shared__ int lcnt[NBUCKET];
    __shared__ int lbase[NBUCKET];
    int tid = threadIdx.x;
    if (tid < NBUCKET) lcnt[tid] = 0;
    __syncthreads();

    int n = blockIdx.x * 1024 + tid;
    bool valid = n < NUM_NETS;
    float4 ra, rb;
    int kx1 = 0, kx2 = 0, ky1 = 0, ky2 = 0;
    if (valid) {
        ra = recA[n]; rb = recB[n];
        unsigned pkx = __float_as_uint(rb.z), pky = __float_as_uint(rb.w);
        kx1 = (int)(pkx & 0xffffu); kx2 = (int)(pkx >> 16);
        ky1 = (int)(pky & 0xffffu); ky2 = (int)(pky >> 16);
#pragma unroll
        for (int cx = 0; cx < 2; ++cx) {
            int kx = cx ? kx2 : kx1;
#pragma unroll
            for (int cy = 0; cy < 2; ++cy) {
                int ky = cy ? ky2 : ky1;
                for_each_bucket(kx, ky, [&](int b) { atomicAdd(&lcnt[b], 1); });
            }
        }
    }
    __syncthreads();
    if (tid < NBUCKET) {
        lbase[tid] = atomicAdd(&gcur[tid], lcnt[tid]);
        lcnt[tid] = 0;
    }
    __syncthreads();
    if (valid) {
        float xmn = ra.x, xmx = ra.y, ymn = ra.z, ymx = ra.w;
        float wh = rb.x, wv = rb.y;
#pragma unroll
        for (int cx = 0; cx < 2; ++cx) {
            int   kx = cx ? kx2 : kx1;
            float xc = cx ? xmx : xmn;
#pragma unroll
            for (int cy = 0; cy < 2; ++cy) {
                int   ky = cy ? ky2 : ky1;
                float yc = cy ? ymx : ymn;
                float sg = (cx ^ cy) ? -1.0f : 1.0f;
                float4 item = make_float4(xc, yc, sg * wh, sg * wv);
                for_each_bucket(kx, ky, [&](int b) {
                    int rank = atomicAdd(&lcnt[b], 1);
                    int pos  = lbase[b] + rank;
                    if (pos < ITEMS_MAX) items[pos] = item;
                });
            }
        }
    }
}

// ---------------------------------------------------------------------------
// D: per-bucket accumulate, 8-deep software-pipelined loads (MLP fix).
// ---------------------------------------------------------------------------
__global__ __launch_bounds__(256) void accum_kernel(
        const float4* __restrict__ items,
        const int* __restrict__ gcnt, const int* __restrict__ goff,
        float* __restrict__ Uh, float* __restrict__ Uv) {
    __shared__ float accH[SW * SLH];    /* 2 KB */
    __shared__ float accV[SW * SLH];    /* 2 KB */
    int b  = blockIdx.x;
    int st = b >> 3, sl = b & 7;
    int x0 = st * SW, y0 = sl * SLH;
    int tid = threadIdx.x;

    for (int k = tid; k < SW * SLH; k += 256) { accH[k] = 0.f; accV[k] = 0.f; }
    __syncthreads();

    int i0  = goff[b];
    int cnt = min(gcnt[b], ITEMS_MAX - i0);
    int end = i0 + cnt;
    if (cnt > 0) {
        for (int q0 = i0 + tid; q0 < end; q0 += UNROLL * 256) {
            /* issue UNROLL independent loads (clamped index keeps them
               unconditional so they all go out back-to-back) */
            float4 a[UNROLL];
            bool   v[UNROLL];
#pragma unroll
            for (int k = 0; k < UNROLL; ++k) {
                int q = q0 + k * 256;
                v[k] = q < end;
                a[k] = items[v[k] ? q : (end - 1)];
            }
#pragma unroll
            for (int k = 0; k < UNROLL; ++k) {
                if (!v[k]) continue;
                float4 it = a[k];
                int kx = min(NB - 1, (int)(it.x * INV_H));
                int ky = min(NB - 1, (int)(it.y * INV_H));
                float dx0 = (kx + 1) * BIN_H - it.x;
                float dx1 = it.x - kx * BIN_H;
                float dy0 = (ky + 1) * BIN_H - it.y;
                float dy1 = it.y - ky * BIN_H;
                int gy = ky - y0;
                bool ok0 = (unsigned)gy < (unsigned)SLH;
                bool ok1 = ((unsigned)(gy + 1) < (unsigned)SLH) && (ky + 1 < NB);
                int c = kx - x0;
#pragma unroll
                for (int cc = 0; cc < 2; ++cc) {
                    int col = c + cc;
                    if ((unsigned)col < SW) {
                        float dx = cc ? dx1 : dx0;
                        if (ok0) {
                            int i = col * SLH + gy;
                            atomicAdd(&accH[i], it.z * dx * dy0);
                            atomicAdd(&accV[i], it.w * dx * dy0);
                        }
                        if (ok1) {
                            int i = col * SLH + gy + 1;
                            atomicAdd(&accH[i], it.z * dx * dy1);
                            atomicAdd(&accV[i], it.w * dx * dy1);
                        }
                    }
                }
            }
        }
    }
    __syncthreads();

    for (int k = tid; k < SW * SLH; k += 256) {
        int col = k >> 6, y = k & (SLH - 1);
        int gi = (x0 + col) * NB + y0 + y;
        Uh[gi] = accH[k];
        Uv[gi] = accV[k];
    }
}

// ---------------------------------------------------------------------------
// E: inclusive y-scan per grid-row (shuffle). 512 blocks x 512 thr.
// ---------------------------------------------------------------------------
__global__ void rowscan_kernel(float* __restrict__ Uh, float* __restrict__ Uv) {
    __shared__ float swh[8], swv[8];
    int x = blockIdx.x, tid = threadIdx.x;
    int lane = tid & 63, wid = tid >> 6;
    float h = Uh[x * NB + tid];
    float v = Uv[x * NB + tid];
#pragma unroll
    for (int o = 1; o < 64; o <<= 1) {
        float a = __shfl_up(h, o);
        float b = __shfl_up(v, o);
        if (lane >= o) { h += a; v += b; }
    }
    if (lane == 63) { swh[wid] = h; swv[wid] = v; }
    __syncthreads();
    float oh = 0.f, ov = 0.f;
    for (int j = 0; j < wid; ++j) { oh += swh[j]; ov += swv[j]; }
    Uh[x * NB + tid] = h + oh;
    Uv[x * NB + tid] = v + ov;
}

// ---------------------------------------------------------------------------
// F: per-stripe partial column scans + totals
// ---------------------------------------------------------------------------
__global__ void colscan_partial_kernel(float* __restrict__ Uh,
                                       float* __restrict__ Uv,
                                       float* __restrict__ totH,
                                       float* __restrict__ totV) {
    int s = blockIdx.x;
    int t = blockIdx.y * blockDim.x + threadIdx.x;
    float h = 0.f, v = 0.f;
#pragma unroll
    for (int i = 0; i < STRIPE; ++i) {
        int row = s * STRIPE + i;
        h += Uh[row * NB + t];  Uh[row * NB + t] = h;
        v += Uv[row * NB + t];  Uv[row * NB + t] = v;
    }
    totH[s * NB + t] = h;
    totV[s * NB + t] = v;
}

// ---------------------------------------------------------------------------
// G: stripe offsets + fused epilogue
// ---------------------------------------------------------------------------
__global__ void colscan_finish_kernel(const float* __restrict__ Uh,
                                      const float* __restrict__ Uv,
                                      const float* __restrict__ totH,
                                      const float* __restrict__ totV,
                                      float* __restrict__ out) {
    int s = blockIdx.x;
    int t = blockIdx.y * blockDim.x + threadIdx.x;
    float offh = 0.f, offv = 0.f;
    for (int s2 = 0; s2 < s; ++s2) {
        offh += totH[s2 * NB + t];
        offv += totV[s2 * NB + t];
    }
#pragma unroll
    for (int i = 0; i < STRIPE; ++i) {
        int row = s * STRIPE + i;
        float h = fabsf(Uh[row * NB + t] + offh) * OUT_SCALE;
        float v = fabsf(Uv[row * NB + t] + offv) * OUT_SCALE;
        float m = fmaxf(h, v);
        out[row * NB + t] = fminf(fmaxf(m * m, 0.5f), 2.0f);
    }
}

// ---------------------------------------------------------------------------
// Fallback (tiny workspace): global-atomic scatter + scans
// ---------------------------------------------------------------------------
__global__ void scatter_kernel(const float* __restrict__ pin_pos,
                               const int*   __restrict__ flat_netpin,
                               const float* __restrict__ net_weights,
                               float* __restrict__ Uh,
                               float* __restrict__ Uv) {
    int n = blockIdx.x * blockDim.x + threadIdx.x;
    if (n >= NUM_NETS) return;
    float xmn = 1e30f, xmx = -1e30f, ymn = 1e30f, ymx = -1e30f;
#pragma unroll
    for (int p = 0; p < PINS_PER_NET; ++p) {
        int pi  = flat_netpin[n * PINS_PER_NET + p];
        float x = pin_pos[pi];
        float y = pin_pos[NUM_PINS + pi];
        xmn = fminf(xmn, x); xmx = fmaxf(xmx, x);
        ymn = fminf(ymn, y); ymx = fmaxf(ymx, y);
    }
    float w  = net_weights[n];
    float wh = w / (ymx - ymn), wv = w / (xmx - xmn);
    int kx1 = min(NB - 1, (int)(xmn * INV_H));
    int kx2 = min(NB - 1, (int)(xmx * INV_H));
    int ky1 = min(NB - 1, (int)(ymn * INV_H));
    int ky2 = min(NB - 1, (int)(ymx * INV_H));
    int   xi[4] = { kx1, kx1 + 1, kx2, kx2 + 1 };
    float xv[4] = { (kx1 + 1) * BIN_H - xmn,  xmn - kx1 * BIN_H,
                    xmx - (kx2 + 1) * BIN_H,  kx2 * BIN_H - xmx };
    int   yi[4] = { ky1, ky1 + 1, ky2, ky2 + 1 };
    float yv[4] = { (ky1 + 1) * BIN_H - ymn,  ymn - ky1 * BIN_H,
                    ymx - (ky2 + 1) * BIN_H,  ky2 * BIN_H - ymx };
#pragma unroll
    for (int a = 0; a < 4; ++a) {
        if (xi[a] >= NB) continue;
#pragma unroll
        for (int b2 = 0; b2 < 4; ++b2) {
            if (yi[b2] >= NB) continue;
            float prod = xv[a] * yv[b2];
            atomicAdd(&Uh[xi[a] * NB + yi[b2]], wh * prod);
            atomicAdd(&Uv[xi[a] * NB + yi[b2]], wv * prod);
        }
    }
}

__global__ void fb_rowscan_kernel(float* __restrict__ Uh, float* __restrict__ Uv) {
    __shared__ float sh[NB];
    __shared__ float sv[NB];
    int rr = blockIdx.x, t = threadIdx.x;
    sh[t] = Uh[rr * NB + t];
    sv[t] = Uv[rr * NB + t];
    __syncthreads();
#pragma unroll
    for (int off = 1; off < NB; off <<= 1) {
        float a = (t >= off) ? sh[t - off] : 0.0f;
        float b = (t >= off) ? sv[t - off] : 0.0f;
        __syncthreads();
        sh[t] += a; sv[t] += b;
        __syncthreads();
    }
    Uh[rr * NB + t] = sh[t];
    Uv[rr * NB + t] = sv[t];
}

__global__ void fb_colscan_kernel(const float* __restrict__ Uh,
                                  const float* __restrict__ Uv,
                                  float* __restrict__ out) {
    int t = blockIdx.x * blockDim.x + threadIdx.x;
    if (t >= NB) return;
    float sh = 0.f, sv = 0.f;
    for (int i = 0; i < NB; ++i) {
        sh += Uh[i * NB + t];
        sv += Uv[i * NB + t];
        float h = fabsf(sh) * OUT_SCALE;
        float v = fabsf(sv) * OUT_SCALE;
        float m = fmaxf(h, v);
        out[i * NB + t] = fminf(fmaxf(m * m, 0.5f), 2.0f);
    }
}

extern "C" void kernel_launch(void* const* d_in, const int* in_sizes, int n_in,
                              void* d_out, int out_size, void* d_ws, size_t ws_size,
                              hipStream_t stream) {
    const float* pin_pos     = (const float*)d_in[0];
    const int*   flat_netpin = (const int*)d_in[2];
    const float* net_weights = (const float*)d_in[3];
    float* out = (float*)d_out;
    float* ws  = (float*)d_ws;

    const size_t o_recA = 0;
    const size_t o_recB = o_recA + (size_t)NUM_NETS * 4;
    const size_t o_pcnt = o_recB + (size_t)NUM_NETS * 4;
    const size_t o_gcnt = o_pcnt + (size_t)NBLK * NBUCKET;
    const size_t o_goff = o_gcnt + NBUCKET;
    const size_t o_gcur = o_goff + NBUCKET;
    const size_t o_itm  = (o_gcur + NBUCKET + 3) & ~(size_t)3;
    const size_t o_Uh   = o_itm + (size_t)ITEMS_MAX * 4;
    const size_t o_Uv   = o_Uh + (size_t)NB * NB;
    const size_t o_Th   = o_Uv + (size_t)NB * NB;
    const size_t o_Tv   = o_Th + (size_t)NSTRIPE * NB;
    const size_t need   = o_Tv + (size_t)NSTRIPE * NB;

    if (ws_size < need * sizeof(float)) {
        float* Uh = ws;
        float* Uv = ws + (size_t)NB * NB;
        hipMemsetAsync(ws, 0, 2 * (size_t)NB * NB * sizeof(float), stream);
        scatter_kernel<<<(NUM_NETS + 255) / 256, 256, 0, stream>>>(
            pin_pos, flat_netpin, net_weights, Uh, Uv);
        fb_rowscan_kernel<<<NB, NB, 0, stream>>>(Uh, Uv);
        fb_colscan_kernel<<<2, 256, 0, stream>>>(Uh, Uv, out);
        return;
    }

    float4* recA  = (float4*)(ws + o_recA);
    float4* recB  = (float4*)(ws + o_recB);
    int*    pcnt  = (int*)(ws + o_pcnt);
    int*    gcnt  = (int*)(ws + o_gcnt);
    int*    goff  = (int*)(ws + o_goff);
    int*    gcur  = (int*)(ws + o_gcur);
    float4* items = (float4*)(ws + o_itm);
    float*  Uh    = ws + o_Uh;
    float*  Uv    = ws + o_Uv;
    float*  Th    = ws + o_Th;
    float*  Tv    = ws + o_Tv;

    bbox_count_kernel<<<NBLK, 1024, 0, stream>>>(
        pin_pos, flat_netpin, net_weights, recA, recB, pcnt);

    offsets_kernel<<<1, 512, 0, stream>>>(pcnt, gcnt, goff, gcur);

    emit_kernel<<<NBLK, 1024, 0, stream>>>(recA, recB, gcur, items);

    accum_kernel<<<NBUCKET, 256, 0, stream>>>(items, gcnt, goff, Uh, Uv);

    rowscan_kernel<<<NB, NB, 0, stream>>>(Uh, Uv);

    colscan_partial_kernel<<<dim3(NSTRIPE, 4), 128, 0, stream>>>(Uh, Uv, Th, Tv);

    colscan_finish_kernel<<<dim3(NSTRIPE, 4), 128, 0, stream>>>(Uh, Uv, Th, Tv, out);
}